// Round 1
// baseline (381.914 us; speedup 1.0000x reference)
//
#include <hip/hip_runtime.h>
#include <math.h>

#define VOL   (128*128*128)   // 2097152 elements per volume
#define PLANE (128*128)       // 16384

// ---------------- reduction helpers ----------------

__device__ __forceinline__ double wave_reduce_d(double v) {
    #pragma unroll
    for (int off = 32; off > 0; off >>= 1)
        v += __shfl_down(v, off, 64);
    return v;
}

__device__ __forceinline__ void block_reduce1_atomic(double a, double* dst) {
    __shared__ double s[4];
    int lane = threadIdx.x & 63;
    int wave = threadIdx.x >> 6;
    a = wave_reduce_d(a);
    if (lane == 0) s[wave] = a;
    __syncthreads();
    if (threadIdx.x == 0) {
        double A = 0.0;
        int nw = blockDim.x >> 6;
        for (int w = 0; w < nw; ++w) A += s[w];
        atomicAdd(&dst[0], A);
    }
}

__device__ __forceinline__ void block_reduce2_atomic(double a, double b, double* dst) {
    __shared__ double s[2][4];
    int lane = threadIdx.x & 63;
    int wave = threadIdx.x >> 6;
    a = wave_reduce_d(a);
    b = wave_reduce_d(b);
    if (lane == 0) { s[0][wave] = a; s[1][wave] = b; }
    __syncthreads();
    if (threadIdx.x == 0) {
        double A = 0.0, B = 0.0;
        int nw = blockDim.x >> 6;
        for (int w = 0; w < nw; ++w) { A += s[0][w]; B += s[1][w]; }
        atomicAdd(&dst[0], A);
        atomicAdd(&dst[1], B);
    }
}

__device__ __forceinline__ void block_reduce3_atomic(double a, double b, double c, double* dst) {
    __shared__ double s[3][4];
    int lane = threadIdx.x & 63;
    int wave = threadIdx.x >> 6;
    a = wave_reduce_d(a);
    b = wave_reduce_d(b);
    c = wave_reduce_d(c);
    if (lane == 0) { s[0][wave] = a; s[1][wave] = b; s[2][wave] = c; }
    __syncthreads();
    if (threadIdx.x == 0) {
        double A = 0.0, B = 0.0, C = 0.0;
        int nw = blockDim.x >> 6;
        for (int w = 0; w < nw; ++w) { A += s[0][w]; B += s[1][w]; C += s[2][w]; }
        atomicAdd(&dst[0], A);
        atomicAdd(&dst[1], B);
        atomicAdd(&dst[2], C);
    }
}

// ---------------- kernels ----------------

// ws layout (doubles):
// [0]      : sum((F_0g - F_0)^2)
// [1..3]   : lcc pair 0: sum(dg*dp), sum(dg^2), sum(dp^2)
// [4..6]   : lcc pair 1
// [7..8]   : tversky 0: sum(g+p), sum(g*p)
// [9..10]  : tversky 1

__global__ void zero_ws_kernel(double* ws) {
    if (threadIdx.x < 16) ws[threadIdx.x] = 0.0;
}

__global__ __launch_bounds__(256) void sqdiff_kernel(const float4* __restrict__ a,
                                                     const float4* __restrict__ b,
                                                     double* dst, int n4) {
    int idx = blockIdx.x * blockDim.x + threadIdx.x;
    int stride = gridDim.x * blockDim.x;
    double acc = 0.0;
    for (int i = idx; i < n4; i += stride) {
        float4 x = a[i], y = b[i];
        float d0 = y.x - x.x, d1 = y.y - x.y, d2 = y.z - x.z, d3 = y.w - x.w;
        acc += (double)(d0 * d0 + d1 * d1) + (double)(d2 * d2 + d3 * d3);
    }
    block_reduce1_atomic(acc, dst);
}

__global__ __launch_bounds__(256) void tversky_kernel(const float4* __restrict__ g,
                                                      const float4* __restrict__ p,
                                                      double* dst, int n4) {
    int idx = blockIdx.x * blockDim.x + threadIdx.x;
    int stride = gridDim.x * blockDim.x;
    double asum = 0.0, aprod = 0.0;
    for (int i = idx; i < n4; i += stride) {
        float4 x = g[i], y = p[i];
        float s = (x.x + y.x) + (x.y + y.y) + (x.z + y.z) + (x.w + y.w);
        float q = (x.x * y.x + x.y * y.y) + (x.z * y.z + x.w * y.w);
        asum += (double)s;
        aprod += (double)q;
    }
    block_reduce2_atomic(asum, aprod, dst);
}

// Fused LCC: per-voxel 5x5x5 box mean (zero padding) of both gt and pred,
// accumulate sum(dg*dp), sum(dg^2), sum(dp^2). One block = 16x16x16 output tile.
__global__ __launch_bounds__(256) void lcc_kernel(const float* __restrict__ gt,
                                                  const float* __restrict__ pred,
                                                  double* dst) {
    __shared__ float lds_g[20 * 20];
    __shared__ float lds_p[20 * 20];
    __shared__ float rs_g[20 * 16];
    __shared__ float rs_p[20 * 16];

    int bx = blockIdx.x;
    int x0 = (bx & 7) << 4;
    int y0 = ((bx >> 3) & 7) << 4;
    int z0 = ((bx >> 6) & 7) << 4;
    int n  = bx >> 9;  // batch 0/1

    const float* G = gt + (size_t)n * VOL;
    const float* P = pred + (size_t)n * VOL;

    int tid = threadIdx.x;
    int lx = tid & 15, ly = tid >> 4;

    float rg0 = 0, rg1 = 0, rg2 = 0, rg3 = 0, rg4 = 0;
    float rp0 = 0, rp1 = 0, rp2 = 0, rp3 = 0, rp4 = 0;
    float a1 = 0, a2 = 0, a3 = 0;

    for (int zp = z0 - 2; zp <= z0 + 17; ++zp) {
        __syncthreads();  // protect lds_* from previous iteration's readers
        bool zin = (zp >= 0) && (zp < 128);
        for (int i = tid; i < 400; i += 256) {
            int r = i / 20;
            int c = i - r * 20;
            int gy = y0 - 2 + r;
            int gx = x0 - 2 + c;
            float vg = 0.0f, vp = 0.0f;
            if (zin && gy >= 0 && gy < 128 && gx >= 0 && gx < 128) {
                size_t off = (size_t)zp * PLANE + (size_t)gy * 128 + gx;
                vg = G[off];
                vp = P[off];
            }
            lds_g[i] = vg;
            lds_p[i] = vp;
        }
        __syncthreads();
        // row sums over x (5-wide), for all 20 halo rows
        for (int i = tid; i < 320; i += 256) {
            int ry = i >> 4, rx = i & 15;
            int b = ry * 20 + rx;
            rs_g[i] = lds_g[b] + lds_g[b + 1] + lds_g[b + 2] + lds_g[b + 3] + lds_g[b + 4];
            rs_p[i] = lds_p[b] + lds_p[b + 1] + lds_p[b + 2] + lds_p[b + 3] + lds_p[b + 4];
        }
        __syncthreads();
        // column sum over y (5-wide) -> plane sum at (ly, lx)
        int rb = ly * 16 + lx;
        float Pg = rs_g[rb] + rs_g[rb + 16] + rs_g[rb + 32] + rs_g[rb + 48] + rs_g[rb + 64];
        float Pp = rs_p[rb] + rs_p[rb + 16] + rs_p[rb + 32] + rs_p[rb + 48] + rs_p[rb + 64];
        // ring shift over z
        rg0 = rg1; rg1 = rg2; rg2 = rg3; rg3 = rg4; rg4 = Pg;
        rp0 = rp1; rp1 = rp2; rp2 = rp3; rp3 = rp4; rp4 = Pp;
        int zout = zp - 2;
        if (zout >= z0) {
            float mg = (rg0 + rg1 + rg2 + rg3 + rg4) * (1.0f / 125.0f);
            float mp = (rp0 + rp1 + rp2 + rp3 + rp4) * (1.0f / 125.0f);
            size_t off = (size_t)zout * PLANE + (size_t)(y0 + ly) * 128 + (x0 + lx);
            float dg = G[off] - mg;
            float dp = P[off] - mp;
            a1 += dg * dp;
            a2 += dg * dg;
            a3 += dp * dp;
        }
    }
    block_reduce3_atomic((double)a1, (double)a2, (double)a3, dst);
}

__global__ void finalize_kernel(const double* __restrict__ ws, float* out) {
    if (threadIdx.x == 0 && blockIdx.x == 0) {
        double reg = sqrt(ws[0]) / 12582912.0;

        double num0 = ws[1] * ws[1];
        double den0 = ws[2] * ws[3];
        if (den0 < 1e-5) den0 = 1e-5;
        double l0 = -(1.0 / 4194304.0) * (num0 / den0);

        double num1 = ws[4] * ws[4];
        double den1 = ws[5] * ws[6];
        if (den1 < 1e-5) den1 = 1e-5;
        double l1 = -(1.0 / 4194304.0) * (num1 / den1);

        double td0 = ws[7]; if (td0 < 1e-5) td0 = 1e-5;
        double t0 = -ws[8] / td0;
        double td1 = ws[9]; if (td1 < 1e-5) td1 = 1e-5;
        double t1 = -ws[10] / td1;

        out[0] = (float)(reg + 10.0 * (l0 + l1) + 10.0 * (t0 + t1));
    }
}

// ---------------- launch ----------------

extern "C" void kernel_launch(void* const* d_in, const int* in_sizes, int n_in,
                              void* d_out, int out_size, void* d_ws, size_t ws_size,
                              hipStream_t stream) {
    double* ws = (double*)d_ws;
    float* out = (float*)d_out;

    const float* F0  = (const float*)d_in[0];
    const float* F0g = (const float*)d_in[1];
    const float* I0  = (const float*)d_in[2];
    const float* I0R = (const float*)d_in[3];
    const float* I1  = (const float*)d_in[4];
    const float* I1R = (const float*)d_in[5];
    const float* S0  = (const float*)d_in[6];
    const float* S0g = (const float*)d_in[7];
    const float* S1  = (const float*)d_in[8];
    const float* S1g = (const float*)d_in[9];

    zero_ws_kernel<<<1, 64, 0, stream>>>(ws);

    // reg field loss: 12,582,912 elements -> 3,145,728 float4
    sqdiff_kernel<<<1024, 256, 0, stream>>>((const float4*)F0, (const float4*)F0g,
                                            &ws[0], 12582912 / 4);

    // tversky: 4,194,304 elements -> 1,048,576 float4
    tversky_kernel<<<512, 256, 0, stream>>>((const float4*)S0, (const float4*)S0g,
                                            &ws[7], 4194304 / 4);
    tversky_kernel<<<512, 256, 0, stream>>>((const float4*)S1, (const float4*)S1g,
                                            &ws[9], 4194304 / 4);

    // fused LCC (box-mean + correlation sums): 1024 blocks cover 2 batches of 128^3
    lcc_kernel<<<1024, 256, 0, stream>>>(I0, I0R, &ws[1]);
    lcc_kernel<<<1024, 256, 0, stream>>>(I1, I1R, &ws[4]);

    finalize_kernel<<<1, 64, 0, stream>>>(ws, out);
}

// Round 2
// 260.553 us; speedup vs baseline: 1.4658x; 1.4658x over previous
//
#include <hip/hip_runtime.h>
#include <math.h>

#define VOL   (128*128*128)   // 2097152 elements per volume
#define PLANE (128*128)       // 16384

// grid partition for mega_kernel
#define LCC_BLOCKS   1024     // 2 pairs x (16 y-tiles x 16 z-tiles x 2 batches)
#define SQ_BLOCKS    1024
#define TV_BLOCKS    256
#define TOTAL_BLOCKS (LCC_BLOCKS + SQ_BLOCKS + 2 * TV_BLOCKS)   // 2560

// ---------------- reduction helpers ----------------

__device__ __forceinline__ double wave_reduce_d(double v) {
    #pragma unroll
    for (int off = 32; off > 0; off >>= 1)
        v += __shfl_down(v, off, 64);
    return v;
}

__device__ __forceinline__ void block_reduce1_atomic(double a, double* dst) {
    __shared__ double s1[4];
    int lane = threadIdx.x & 63;
    int wave = threadIdx.x >> 6;
    a = wave_reduce_d(a);
    if (lane == 0) s1[wave] = a;
    __syncthreads();
    if (threadIdx.x == 0) {
        double A = s1[0] + s1[1] + s1[2] + s1[3];
        atomicAdd(&dst[0], A);
    }
}

__device__ __forceinline__ void block_reduce2_atomic(double a, double b, double* dst) {
    __shared__ double s2[2][4];
    int lane = threadIdx.x & 63;
    int wave = threadIdx.x >> 6;
    a = wave_reduce_d(a);
    b = wave_reduce_d(b);
    if (lane == 0) { s2[0][wave] = a; s2[1][wave] = b; }
    __syncthreads();
    if (threadIdx.x == 0) {
        atomicAdd(&dst[0], s2[0][0] + s2[0][1] + s2[0][2] + s2[0][3]);
        atomicAdd(&dst[1], s2[1][0] + s2[1][1] + s2[1][2] + s2[1][3]);
    }
}

__device__ __forceinline__ void block_reduce3_atomic(double a, double b, double c, double* dst) {
    __shared__ double s3[3][4];
    int lane = threadIdx.x & 63;
    int wave = threadIdx.x >> 6;
    a = wave_reduce_d(a);
    b = wave_reduce_d(b);
    c = wave_reduce_d(c);
    if (lane == 0) { s3[0][wave] = a; s3[1][wave] = b; s3[2][wave] = c; }
    __syncthreads();
    if (threadIdx.x == 0) {
        atomicAdd(&dst[0], s3[0][0] + s3[0][1] + s3[0][2] + s3[0][3]);
        atomicAdd(&dst[1], s3[1][0] + s3[1][1] + s3[1][2] + s3[1][3]);
        atomicAdd(&dst[2], s3[2][0] + s3[2][1] + s3[2][2] + s3[2][3]);
    }
}

// ---------------- ws layout (doubles) ----------------
// [0]      : sum((F_0g - F_0)^2)
// [1..3]   : lcc pair 0: sum(dg*dp), sum(dg^2), sum(dp^2)
// [4..6]   : lcc pair 1
// [7..8]   : tversky 0: sum(g+p), sum(g*p)
// [9..10]  : tversky 1

__global__ void zero_ws_kernel(double* ws) {
    if (threadIdx.x < 16) ws[threadIdx.x] = 0.0;
}

// ---------------- mega kernel ----------------
// Blocks [0,1024): fused LCC (both pairs).  Tile: x=full 128, y=8, z=8.
//   Thread (x = tid&127, g = tid>>7): g selects volume (0=gt, 1=pred).
//   y-box-sum in registers (thread owns the whole y-column), x-box-sum via
//   LDS (stride-1, conflict free), z via 5-deep register ring, fully
//   unrolled 12-plane loop with prefetch of plane z+1 issued pre-barrier.
// Blocks [1024,2048): sqdiff (reg_field_loss numerator)
// Blocks [2048,2560): tversky x2

__global__ __launch_bounds__(256) void mega_kernel(
    const float* __restrict__ F0,  const float* __restrict__ F0g,
    const float* __restrict__ I0,  const float* __restrict__ I0R,
    const float* __restrict__ I1,  const float* __restrict__ I1R,
    const float* __restrict__ S0,  const float* __restrict__ S0g,
    const float* __restrict__ S1,  const float* __restrict__ S1g,
    double* __restrict__ ws)
{
    int b = blockIdx.x;
    int tid = threadIdx.x;

    if (b < LCC_BLOCKS) {
        __shared__ float ybuf[2 * 8 * 128];   // [g][k][x] y-box-sums
        __shared__ float dbuf[8 * 128];       // d_pred exchange

        int pair = b >> 9;
        int r  = b & 511;
        int y0 = (r & 15) << 3;
        int z0 = ((r >> 4) & 15) << 3;
        int n  = r >> 8;

        const float* gt = pair ? I1  : I0;
        const float* pr = pair ? I1R : I0R;
        double* dst = ws + (pair ? 4 : 1);

        int x = tid & 127;
        int g = tid >> 7;                      // wave-uniform (waves 0,1 vs 2,3)
        const float* V = (g ? pr : gt) + (size_t)n * VOL;

        float a1 = 0.f, a2 = 0.f, a3 = 0.f;
        float ps[5][8];                        // z-ring of 2D plane sums
        float cent1[8], cent2[8];              // raw center values, z-2 ring
        float v[12];

        float* yb = ybuf + g * 1024;

        // preload plane z0-2
        {
            int zp = z0 - 2;
            bool zin = (zp >= 0);
            #pragma unroll
            for (int j = 0; j < 12; ++j) {
                int gy = y0 - 2 + j;
                v[j] = (zin && gy >= 0 && gy < 128)
                         ? V[(size_t)zp * PLANE + (size_t)gy * 128 + x] : 0.0f;
            }
        }

        #pragma unroll
        for (int it = 0; it < 12; ++it) {
            int zp = z0 - 2 + it;
            // y-box-sums (registers only) -> LDS
            #pragma unroll
            for (int k = 0; k < 8; ++k)
                yb[k * 128 + x] = v[k] + v[k+1] + v[k+2] + v[k+3] + v[k+4];

            // prefetch next plane (issued before the barrier)
            float vn[12];
            if (it < 11) {
                int zq = zp + 1;
                bool zin = (zq < 128);         // zq >= z0-1 >= -1; zq==-1 only if z0==0,it... zq>=z0-1>=... guard both
                bool zlo = (zq >= 0);
                #pragma unroll
                for (int j = 0; j < 12; ++j) {
                    int gy = y0 - 2 + j;
                    vn[j] = (zin && zlo && gy >= 0 && gy < 128)
                              ? V[(size_t)zq * PLANE + (size_t)gy * 128 + x] : 0.0f;
                }
            }
            __syncthreads();

            // x-box-sum (stride-1 LDS reads, zero-pad at x edges)
            #pragma unroll
            for (int k = 0; k < 8; ++k) {
                float s = yb[k * 128 + x];
                if (x >= 2)   s += yb[k * 128 + x - 2];
                if (x >= 1)   s += yb[k * 128 + x - 1];
                if (x <= 126) s += yb[k * 128 + x + 1];
                if (x <= 125) s += yb[k * 128 + x + 2];
                ps[it % 5][k] = s;
            }

            float d[8];
            if (it >= 4) {
                #pragma unroll
                for (int k = 0; k < 8; ++k) {
                    float m = (ps[0][k] + ps[1][k] + ps[2][k] + ps[3][k] + ps[4][k])
                              * (1.0f / 125.0f);
                    d[k] = cent2[k] - m;       // cent2 holds plane zp-2 raw values
                }
                if (g) {
                    #pragma unroll
                    for (int k = 0; k < 8; ++k) {
                        dbuf[k * 128 + x] = d[k];
                        a3 += d[k] * d[k];
                    }
                }
            }
            __syncthreads();
            if (it >= 4 && g == 0) {
                #pragma unroll
                for (int k = 0; k < 8; ++k) {
                    float dp = dbuf[k * 128 + x];
                    a1 += d[k] * dp;
                    a2 += d[k] * d[k];
                }
            }

            // shift center ring, advance plane
            #pragma unroll
            for (int k = 0; k < 8; ++k) { cent2[k] = cent1[k]; cent1[k] = v[k + 2]; }
            if (it < 11) {
                #pragma unroll
                for (int j = 0; j < 12; ++j) v[j] = vn[j];
            }
        }
        block_reduce3_atomic((double)a1, (double)a2, (double)a3, dst);

    } else if (b < LCC_BLOCKS + SQ_BLOCKS) {
        // reg field loss numerator: 12,582,912 elems = 3,145,728 float4
        int bid = b - LCC_BLOCKS;
        const float4* A = (const float4*)F0;
        const float4* B = (const float4*)F0g;
        int n4 = 12582912 / 4;
        int idx = bid * 256 + tid;
        int stride = SQ_BLOCKS * 256;
        float acc = 0.f;
        for (int i = idx; i < n4; i += stride) {
            float4 xx = A[i], yy = B[i];
            float d0 = yy.x - xx.x, d1 = yy.y - xx.y;
            float d2 = yy.z - xx.z, d3 = yy.w - xx.w;
            acc += (d0 * d0 + d1 * d1) + (d2 * d2 + d3 * d3);
        }
        block_reduce1_atomic((double)acc, &ws[0]);

    } else {
        // tversky: 4,194,304 elems = 1,048,576 float4 per pair
        int bid = b - (LCC_BLOCKS + SQ_BLOCKS);
        int pair = bid >= TV_BLOCKS;
        bid -= pair ? TV_BLOCKS : 0;
        const float4* Gp = (const float4*)(pair ? S1 : S0);
        const float4* Pp = (const float4*)(pair ? S1g : S0g);
        double* dst = ws + (pair ? 9 : 7);
        int n4 = 4194304 / 4;
        int idx = bid * 256 + tid;
        int stride = TV_BLOCKS * 256;
        float asum = 0.f, aprod = 0.f;
        for (int i = idx; i < n4; i += stride) {
            float4 xx = Gp[i], yy = Pp[i];
            asum  += (xx.x + yy.x) + (xx.y + yy.y) + (xx.z + yy.z) + (xx.w + yy.w);
            aprod += (xx.x * yy.x + xx.y * yy.y) + (xx.z * yy.z + xx.w * yy.w);
        }
        block_reduce2_atomic((double)asum, (double)aprod, dst);
    }
}

__global__ void finalize_kernel(const double* __restrict__ ws, float* out) {
    if (threadIdx.x == 0 && blockIdx.x == 0) {
        double reg = sqrt(ws[0]) / 12582912.0;

        double num0 = ws[1] * ws[1];
        double den0 = ws[2] * ws[3];
        if (den0 < 1e-5) den0 = 1e-5;
        double l0 = -(1.0 / 4194304.0) * (num0 / den0);

        double num1 = ws[4] * ws[4];
        double den1 = ws[5] * ws[6];
        if (den1 < 1e-5) den1 = 1e-5;
        double l1 = -(1.0 / 4194304.0) * (num1 / den1);

        double td0 = ws[7]; if (td0 < 1e-5) td0 = 1e-5;
        double t0 = -ws[8] / td0;
        double td1 = ws[9]; if (td1 < 1e-5) td1 = 1e-5;
        double t1 = -ws[10] / td1;

        out[0] = (float)(reg + 10.0 * (l0 + l1) + 10.0 * (t0 + t1));
    }
}

// ---------------- launch ----------------

extern "C" void kernel_launch(void* const* d_in, const int* in_sizes, int n_in,
                              void* d_out, int out_size, void* d_ws, size_t ws_size,
                              hipStream_t stream) {
    double* ws = (double*)d_ws;
    float* out = (float*)d_out;

    const float* F0  = (const float*)d_in[0];
    const float* F0g = (const float*)d_in[1];
    const float* I0  = (const float*)d_in[2];
    const float* I0R = (const float*)d_in[3];
    const float* I1  = (const float*)d_in[4];
    const float* I1R = (const float*)d_in[5];
    const float* S0  = (const float*)d_in[6];
    const float* S0g = (const float*)d_in[7];
    const float* S1  = (const float*)d_in[8];
    const float* S1g = (const float*)d_in[9];

    zero_ws_kernel<<<1, 64, 0, stream>>>(ws);
    mega_kernel<<<TOTAL_BLOCKS, 256, 0, stream>>>(F0, F0g, I0, I0R, I1, I1R,
                                                  S0, S0g, S1, S1g, ws);
    finalize_kernel<<<1, 64, 0, stream>>>(ws, out);
}